// Round 4
// baseline (993.833 us; speedup 1.0000x reference)
//
#include <hip/hip_runtime.h>

// ResidualVectorQuantizer, MI355X. fp16 hi/lo MFMA distance scores + exact
// top-2 tracking; near-ties re-ranked by BIT-EXACT emulation of the numpy
// float32 reference:
//   d = np.sum(r*r,1,keepdims) + np.sum(e*e,1) - (2.0*r) @ emb.T
//   np.sum(256): pairwise split 128+128; base = AVX512 npyv (8 zmm accums,
//                vector combine tree, _mm512_reduce_add_ps gcc tree)  [SUMTOPO 2]
//   matmul:     sgemm k-sequential single-accumulator FMA chain
// Residual update replicates the reference's fp32 3-op chain exactly.
// SUMTOPO: 0=scalar pw128+pw128, 1=skip-first scalar pairwise(255), 2=AVX512 SIMD
#define SUMTOPO 2

#define NUM_Q   4
#define KCODE   1024
#define DIM     256
#define NROWS   131072
#define QELEMS  33554432
#define MARGIN  3e-3f

typedef _Float16 f16x8 __attribute__((ext_vector_type(8)));
typedef float    f32x4 __attribute__((ext_vector_type(4)));

// ---------------------------------------------------------------- prep
__global__ __launch_bounds__(64) void rvq_prep(const float* __restrict__ emb,
                                               _Float16* __restrict__ efrag,
                                               float* __restrict__ e2,
                                               double* __restrict__ loss)
{
    const int bid  = blockIdx.x;            // layer*64 + tile
    const int lane = threadIdx.x;           // 0..63
    const int layer = bid >> 6, tile = bid & 63;
    const int c = tile*16 + (lane & 15);    // code handled by this lane
    const int g = lane >> 4;                // k-chunk group
    const float* ep = emb + ((size_t)layer*KCODE + c)*DIM;

    double s2 = 0.0;
    #pragma unroll
    for (int j = 0; j < 8; ++j) {
        const int k0 = j*32 + 8*g;
        float4 a = *(const float4*)(ep + k0);
        float4 b = *(const float4*)(ep + k0 + 4);
        float v[8] = {a.x,a.y,a.z,a.w,b.x,b.y,b.z,b.w};
        f16x8 hh, ll;
        #pragma unroll
        for (int x = 0; x < 8; ++x) {
            double dv = (double)v[x];
            s2 += dv*dv;
            float m2 = -2.0f*v[x];               // fold -2 exactly
            _Float16 h = (_Float16)m2;
            hh[x] = h;
            ll[x] = (_Float16)((m2 - (float)h)*4096.0f);  // scaled lo
        }
        size_t base = (((size_t)(bid*8 + j)*2 + 0)*64 + lane)*8;
        *(f16x8*)(efrag + base)       = hh;      // hl=0
        *(f16x8*)(efrag + base + 512) = ll;      // hl=1 (+64*8)
    }
    s2 += __shfl_xor(s2, 16);
    s2 += __shfl_xor(s2, 32);
    if (g == 0) e2[layer*KCODE + c] = (float)s2;
    if (bid == 0 && lane < 4) loss[lane] = 0.0;
}

// ---------------- numpy float32 sum-of-256 emulations -----------------
// scalar pairwise base for n in [8,128] (numpy loops.c.src)
__device__ __forceinline__ float np_pw_base(const float* v, int n) {
    #pragma clang fp contract(off)
    float r[8];
    #pragma unroll
    for (int j = 0; j < 8; ++j) r[j] = v[j];
    int i = 8;
    for (; i < n - (n % 8); i += 8) {
        #pragma unroll
        for (int j = 0; j < 8; ++j) r[j] = r[j] + v[i+j];
    }
    float res = ((r[0] + r[1]) + (r[2] + r[3])) + ((r[4] + r[5]) + (r[6] + r[7]));
    for (; i < n; ++i) res = res + v[i];
    return res;
}

// AVX512 npyv base for one 128-block + gcc _mm512_reduce_add_ps tree
__device__ __forceinline__ float np_simd512_128(const float* p) {
    #pragma clang fp contract(off)
    float s[16], U[4];
    #pragma unroll
    for (int l = 0; l < 16; ++l) {
        s[l] = ((p[l] + p[16+l]) + (p[32+l] + p[48+l]))
             + ((p[64+l] + p[80+l]) + (p[96+l] + p[112+l]));
    }
    #pragma unroll
    for (int i = 0; i < 4; ++i) U[i] = (s[i] + s[i+8]) + (s[i+4] + s[i+12]);
    return (U[0] + U[2]) + (U[1] + U[3]);
}

__device__ __forceinline__ float np_sum256(const float* v) {
    #pragma clang fp contract(off)
#if SUMTOPO == 0
    return np_pw_base(v, 128) + np_pw_base(v + 128, 128);
#elif SUMTOPO == 1
    // skip-first: a[0] + pairwise(a+1, 255); 255 -> 120 + (64 + 71)
    float right = np_pw_base(v + 121, 64) + np_pw_base(v + 185, 71);
    return v[0] + (np_pw_base(v + 1, 120) + right);
#else
    return np_simd512_128(v) + np_simd512_128(v + 128);
#endif
}

// ---------------------------------------------------------------- layer
__global__ __launch_bounds__(256, 2) void rvq_layer(
    const float* __restrict__ rin, float* __restrict__ rout,
    const float* __restrict__ emb,       // this layer's raw embeddings [1024][256]
    const _Float16* __restrict__ efrag,  // this layer's frag base
    const float* __restrict__ e2,        // this layer's e2 [1024]
    float* __restrict__ idx_out,         // indices region (float) for this layer
    double* __restrict__ loss_slot)
{
    __shared__ __align__(16) _Float16 lt[2][8][2][64][8]; // 2 x 16KB tile dbuf
    __shared__ __align__(16) float    e2l[KCODE];
    __shared__ __align__(16) float    s_remu[4][DIM];     // per-wave r row (emulation)
    __shared__ double wsum[4];

    const int tid  = threadIdx.x;
    const int w    = tid >> 6;
    const int lane = tid & 63;
    const int col  = lane & 15;          // residual-row-within-16
    const int g    = lane >> 4;
    const int r0   = blockIdx.x*128 + w*32;

    {
        f32x4 v = *(const f32x4*)(e2 + tid*4);
        *(f32x4*)(e2l + tid*4) = v;
    }

    // B-fragments: 32 residual rows, full K=256, fp16 hi + scaled lo
    f16x8 rh[2][8], rl[2][8];
    #pragma unroll
    for (int t = 0; t < 2; ++t) {
        const float* rp = rin + (size_t)(r0 + 16*t + col)*DIM + 8*g;
        #pragma unroll
        for (int j = 0; j < 8; ++j) {
            float4 a = *(const float4*)(rp + j*32);
            float4 b = *(const float4*)(rp + j*32 + 4);
            float v[8] = {a.x,a.y,a.z,a.w,b.x,b.y,b.z,b.w};
            #pragma unroll
            for (int x = 0; x < 8; ++x) {
                _Float16 h = (_Float16)v[x];
                rh[t][j][x] = h;
                rl[t][j][x] = (_Float16)((v[x] - (float)h)*4096.0f);
            }
        }
    }

    const uint4* gsrc = (const uint4*)efrag;      // 1024 uint4 per 16KB tile
    {
        uint4 s0 = gsrc[tid], s1 = gsrc[256+tid], s2 = gsrc[512+tid], s3 = gsrc[768+tid];
        uint4* lw = (uint4*)&lt[0][0][0][0][0];
        lw[tid] = s0; lw[256+tid] = s1; lw[512+tid] = s2; lw[768+tid] = s3;
    }
    __syncthreads();

    float m1[2]  = {3.4e38f, 3.4e38f};
    float m2v[2] = {3.4e38f, 3.4e38f};
    int   i1[2]  = {0, 0};
    int   i2[2]  = {0, 0};

    for (int ct = 0; ct < 64; ++ct) {
        const int cur = ct & 1;
        uint4 p0, p1, p2, p3;
        if (ct < 63) {
            const uint4* gn = gsrc + (size_t)(ct+1)*1024;
            p0 = gn[tid]; p1 = gn[256+tid]; p2 = gn[512+tid]; p3 = gn[768+tid];
        }
        f32x4 acch[2] = {{0.f,0.f,0.f,0.f},{0.f,0.f,0.f,0.f}};
        f32x4 accl[2] = {{0.f,0.f,0.f,0.f},{0.f,0.f,0.f,0.f}};
        #pragma unroll
        for (int j = 0; j < 8; ++j) {
            f16x8 ah = *(const f16x8*)&lt[cur][j][0][lane][0];
            f16x8 al = *(const f16x8*)&lt[cur][j][1][lane][0];
            acch[0] = __builtin_amdgcn_mfma_f32_16x16x32_f16(ah, rh[0][j], acch[0], 0,0,0);
            acch[1] = __builtin_amdgcn_mfma_f32_16x16x32_f16(ah, rh[1][j], acch[1], 0,0,0);
            accl[0] = __builtin_amdgcn_mfma_f32_16x16x32_f16(al, rh[0][j], accl[0], 0,0,0);
            accl[1] = __builtin_amdgcn_mfma_f32_16x16x32_f16(al, rh[1][j], accl[1], 0,0,0);
            accl[0] = __builtin_amdgcn_mfma_f32_16x16x32_f16(ah, rl[0][j], accl[0], 0,0,0);
            accl[1] = __builtin_amdgcn_mfma_f32_16x16x32_f16(ah, rl[1][j], accl[1], 0,0,0);
        }
        f32x4 e2v = *(const f32x4*)(e2l + ct*16 + 4*g);
        #pragma unroll
        for (int t = 0; t < 2; ++t) {
            #pragma unroll
            for (int r = 0; r < 4; ++r) {
                float s = acch[t][r] + accl[t][r]*(1.0f/4096.0f) + e2v[r];
                int   k = ct*16 + 4*g + r;
                bool c1 = s < m1[t];
                bool c2 = s < m2v[t];
                m2v[t] = c1 ? m1[t] : (c2 ? s : m2v[t]);
                i2[t]  = c1 ? i1[t] : (c2 ? k : i2[t]);
                m1[t]  = c1 ? s : m1[t];
                i1[t]  = c1 ? k : i1[t];
            }
        }
        __syncthreads();
        if (ct < 63) {
            uint4* lw = (uint4*)&lt[cur^1][0][0][0][0];
            lw[tid] = p0; lw[256+tid] = p1; lw[512+tid] = p2; lw[768+tid] = p3;
        }
        __syncthreads();
    }

    // merge per-lane top-2 across the 4 code-subsets (xor 16, 32); exact.
    #pragma unroll
    for (int t = 0; t < 2; ++t) {
        #pragma unroll
        for (int off = 16; off < 64; off <<= 1) {
            float om1 = __shfl_xor(m1[t], off), om2 = __shfl_xor(m2v[t], off);
            int   oi1 = __shfl_xor(i1[t], off), oi2 = __shfl_xor(i2[t], off);
            bool aL = (m1[t] < om1) || (m1[t] == om1 && i1[t] < oi1);
            float M1 = aL ? m1[t] : om1;  int I1 = aL ? i1[t] : oi1;
            float cv = aL ? om1 : m1[t];  int ci = aL ? oi1 : i1[t];
            float sv = aL ? m2v[t] : om2; int si = aL ? i2[t] : oi2;
            bool bL = (cv < sv) || (cv == sv && ci < si);
            m2v[t] = bL ? cv : sv; i2[t] = bL ? ci : si;
            m1[t] = M1; i1[t] = I1;
        }
    }

    // ---- near-tie re-ranking: bit-exact numpy-fp32 emulation of
    //      d = npsum(r*r) + npsum(e*e) - 2*(sequential-FMA dot(r,e))
    #pragma unroll
    for (int t = 0; t < 2; ++t) {
        bool flag = (m2v[t] - m1[t]) < MARGIN;
        unsigned long long mask = __ballot(flag) & 0xFFFFull;   // lane<16 reps
        while (mask) {
            int lnp = __ffsll((unsigned long long)mask) - 1; mask &= mask - 1;
            int row = r0 + 16*t + lnp;
            int ca = __shfl(i1[t], lnp);
            int cb = __shfl(i2[t], lnp);
            // stage r row to LDS in k order
            float4 rv = *(const float4*)(rin + (size_t)row*DIM + 4*lane);
            *(float4*)&s_remu[w][4*lane] = rv;
            asm volatile("s_waitcnt lgkmcnt(0)" ::: "memory");
            float d;
            {
                #pragma clang fp contract(off)
                const int   cand = (lane == 0) ? ca : cb;
                const float* ep  = emb + (size_t)cand*DIM;
                const float* rp  = &s_remu[w][0];
                // sequential single-accumulator FMA chain (BLAS microkernel order)
                float m = 0.f;
                for (int k = 0; k < DIM; ++k) m = __builtin_fmaf(rp[k], ep[k], m);
                // numpy sums of individually-rounded squares
                float tmp[DIM];
                for (int k = 0; k < DIM; ++k) tmp[k] = ep[k]*ep[k];
                float se = np_sum256(tmp);
                for (int k = 0; k < DIM; ++k) tmp[k] = rp[k]*rp[k];
                float sr = np_sum256(tmp);
                d = (sr + se) - 2.0f*m;          // (2r)@e.T == 2*m exactly
            }
            float da = __shfl(d, 0), db = __shfl(d, 1);
            int wnr = (db < da) ? cb : ((da < db) ? ca : (ca < cb ? ca : cb));
            if (col == lnp) i1[t] = wnr;
        }
    }

    // write indices (as float) for this wave's 32 rows
    if (lane < 32) {
        int v = (lane < 16) ? i1[0] : i1[1];
        idx_out[r0 + lane] = (float)v;
    }

    // epilogue: replicate reference fp32 residual chain per element:
    // tq = fl(q - r); qst = fl(r + tq); r' = fl(r - qst)
    double lacc = 0.0;
    #pragma unroll 4
    for (int i = 0; i < 32; ++i) {
        #pragma clang fp contract(off)
        int kr = __shfl((i < 16) ? i1[0] : i1[1], i & 15);
        int row = r0 + i;
        float4 rv = *(const float4*)(rin + (size_t)row*DIM + 4*lane);
        float4 ev = *(const float4*)(emb + (size_t)kr*DIM + 4*lane);
        float t0 = ev.x - rv.x, t1g = ev.y - rv.y, t2g = ev.z - rv.z, t3g = ev.w - rv.w;
        float q0 = rv.x + t0,  q1 = rv.y + t1g,  q2 = rv.z + t2g,  q3 = rv.w + t3g;
        float4 nv;
        nv.x = rv.x - q0; nv.y = rv.y - q1; nv.z = rv.z - q2; nv.w = rv.w - q3;
        *(float4*)(rout + (size_t)row*DIM + 4*lane) = nv;
        lacc += (double)(t0*t0) + (double)(t1g*t1g) + (double)(t2g*t2g) + (double)(t3g*t3g);
    }
    #pragma unroll
    for (int o = 32; o; o >>= 1) lacc += __shfl_xor(lacc, o);
    if (lane == 0) wsum[w] = lacc;
    __syncthreads();
    if (tid == 0) atomicAdd(loss_slot, wsum[0]+wsum[1]+wsum[2]+wsum[3]);
}

// ---------------------------------------------------------------- final
__global__ void rvq_final(const float* __restrict__ x, float* __restrict__ outq,
                          const double* __restrict__ loss, float* __restrict__ lossout)
{
    size_t i = (size_t)blockIdx.x*blockDim.x + threadIdx.x;
    size_t stride = (size_t)gridDim.x*blockDim.x;
    const float4* x4 = (const float4*)x;
    float4* o4 = (float4*)outq;
    for (size_t e = i; e < (size_t)QELEMS/4; e += stride) {
        float4 xv = x4[e];
        float4 rv = o4[e];
        float4 o; o.x = xv.x - rv.x; o.y = xv.y - rv.y; o.z = xv.z - rv.z; o.w = xv.w - rv.w;
        o4[e] = o;   // quantized_out = x - r_final
    }
    if (blockIdx.x == 0 && threadIdx.x == 0) {
        double tot = (loss[0]+loss[1]+loss[2]+loss[3]) * (1.0/(double)QELEMS);
        lossout[0] = (float)(1.25*tot);   // vq_loss
        lossout[1] = (float)(0.25*tot);   // commit_loss
        lossout[2] = (float)tot;          // codebook_loss
    }
}

// ---------------------------------------------------------------- launch
extern "C" void kernel_launch(void* const* d_in, const int* in_sizes, int n_in,
                              void* d_out, int out_size, void* d_ws, size_t ws_size,
                              hipStream_t stream)
{
    (void)in_sizes; (void)n_in; (void)out_size; (void)ws_size;
    const float* x   = (const float*)d_in[0];
    const float* emb = (const float*)d_in[1];
    float* out      = (float*)d_out;
    float* rbuf     = out;                         // residual lives in quantized region
    float* idx_base = out + QELEMS;                // indices-as-float (NUM_Q, 16, 8192)
    float* loss_out = out + QELEMS + (size_t)NUM_Q*NROWS;

    _Float16* efrag = (_Float16*)d_ws;                              // 4 MB
    float*    e2    = (float*)((char*)d_ws + 4u*1024u*1024u);       // 16 KB
    double*   loss  = (double*)((char*)d_ws + 4u*1024u*1024u + 16384u);

    rvq_prep<<<NUM_Q*64, 64, 0, stream>>>(emb, efrag, e2, loss);
    for (int q = 0; q < NUM_Q; ++q) {
        const float* rin = (q == 0) ? x : rbuf;
        rvq_layer<<<NROWS/128, 256, 0, stream>>>(
            rin, rbuf,
            emb   + (size_t)q*KCODE*DIM,
            efrag + (size_t)q*64*8192,
            e2    + (size_t)q*KCODE,
            idx_base + (size_t)q*NROWS,
            loss + q);
    }
    rvq_final<<<2048, 256, 0, stream>>>(x, rbuf, loss, loss_out);
}